// Round 1
// baseline (767.650 us; speedup 1.0000x reference)
//
#include <hip/hip_runtime.h>
#include <hip/hip_bf16.h>
#include <math.h>
#include <stdint.h>

// Problem constants
#define BB   256
#define NN   180
#define CC   768
#define RR   192
#define MROWS (BB*NN)      // 46080 flat rows
#define KPAD 192           // node-dim padded to 192 for GEMM3 K

typedef __attribute__((ext_vector_type(8))) __bf16 bf16x8;
typedef __attribute__((ext_vector_type(4))) __bf16 bf16x4;
typedef __attribute__((ext_vector_type(4))) float  floatx4;

// async global->LDS, 16 B per lane. LDS dest is wave-uniform base + lane*16.
__device__ __forceinline__ void gload_lds16(const __bf16* g, __bf16* lds)
{
    __builtin_amdgcn_global_load_lds(
        (const __attribute__((address_space(1))) void*)(uintptr_t)(const void*)g,
        (__attribute__((address_space(3))) void*)(uintptr_t)(void*)lds,
        16, 0, 0);
}

// ---------------------------------------------------------------------------
// gemm256: 256x256-tile, BK=64, 8 waves (512 thr), 8-phase counted-vmcnt
// schedule (T3+T4), XOR-swizzled LDS (T2), setprio around MFMA (T5),
// bijective XCD blockIdx swizzle (T1). B transposed (Bt[n][k]).
//
// LDS = 128 KB dynamic: per operand 4 regions of [256 rows][32 k] bf16
// (region = buf*2 + khalf). Swizzle: within a 64B row, phys 16B-slot =
// logical_slot ^ ((row>>1)&3); applied on the per-lane GLOBAL source addr
// (LDS dest stays linear, rule #21) and identically on ds_read addrs.
//
// Staging granule = one (operand, khalf) region = 16 KB = 2 gload/wave.
// Per iteration (tiles t0=2i buf0, t1=2i+1 buf1), phases 0..7:
//   ph0: rd buf0.k0 mg0 | stage A-k1(t1)  ->rA3
//   ph1: rd buf0.k0 mg1 | stage B-k1(t1)  ->rB3   vmcnt(8)
//   ph2: rd buf0.k1 mg0 | stage A-k0(t+2) ->rA0
//   ph3: rd buf0.k1 mg1 | stage B-k0(t+2) ->rB0   vmcnt(8)
//   ph4: rd buf1.k0 mg0 | stage A-k1(t+2) ->rA1
//   ph5: rd buf1.k0 mg1 | stage B-k1(t+2) ->rB1   vmcnt(8)
//   ph6: rd buf1.k1 mg0 | stage A-k0(t+3) ->rA2
//   ph7: rd buf1.k1 mg1 | stage B-k0(t+3) ->rB2   vmcnt(8)
// Steady state: 12 gloads outstanding at each check, drain oldest 4 (the
// granule needed 1 phase later). Tail: tile index clamped to NT-1 so the
// counts stay uniform (over-staged data is never read). Requires K%128==0.
// MODE 0: out bf16, val=(acc+bias[n])*scale[n]
// MODE 3: out f32,  val=relu(acc+bias[n]) + addx[m*ldc+n]
// ---------------------------------------------------------------------------
template<int MODE>
__global__ __launch_bounds__(512, 2) void gemm256(
    const __bf16* __restrict__ A,  int lda,
    const __bf16* __restrict__ Bt, int ldb,
    void* __restrict__ Cout, int ldc,
    int M, int N, int K,
    const float* __restrict__ bias,
    const float* __restrict__ scale,
    const float* __restrict__ addx)
{
    extern __shared__ __align__(128) __bf16 smem[];
    __bf16 (*sA)[8192] = (__bf16 (*)[8192])(smem);           // 4 x 16 KB
    __bf16 (*sB)[8192] = (__bf16 (*)[8192])(smem + 32768);   // 4 x 16 KB

    // bijective XCD swizzle (m204): contiguous tile chunk per XCD
    const int nwg = gridDim.x * gridDim.y;
    const int lin = blockIdx.y * gridDim.x + blockIdx.x;
    const int qd = nwg >> 3, rr = nwg & 7, xc = lin & 7, oo = lin >> 3;
    const int wg = (xc < rr ? xc * (qd + 1) : rr * (qd + 1) + (xc - rr) * qd) + oo;
    const int n0 = (wg % gridDim.x) * 256;
    const int m0 = (wg / gridDim.x) * 256;

    const int t  = threadIdx.x;
    const int w  = t >> 6;            // wave 0..7
    const int l  = t & 63;
    const int lr = l & 15;
    const int q  = l >> 4;
    const int wm = w >> 2;            // 0..1 : rows wm*128
    const int wn = w & 3;             // 0..3 : cols wn*64
    const int xr = (lr >> 1) & 3;     // read-side swizzle factor

    // ds_read base offsets (elements); per-frag adds are compile-time imms
    const int a_base = (wm * 128 + lr) * 32 + ((q ^ xr) * 8);
    const int b_base = (wn * 64  + lr) * 32 + ((q ^ xr) * 8);

    // staging lane map: instr covers 16 rows x 64B; lane l -> row l>>2,
    // phys slot l&3 holds logical slot (l&3)^((l>>3)&3)  (source pre-swizzle)
    const int srow = l >> 2;
    const int slog = (l & 3) ^ ((l >> 3) & 3);

    int ar0 = m0 + w * 32 + srow;       if (ar0 > M - 1) ar0 = M - 1;
    int ar1 = m0 + w * 32 + 16 + srow;  if (ar1 > M - 1) ar1 = M - 1;
    int br0 = n0 + w * 32 + srow;       if (br0 > N - 1) br0 = N - 1;
    int br1 = n0 + w * 32 + 16 + srow;  if (br1 > N - 1) br1 = N - 1;

    const __bf16* pA0 = A  + (long)ar0 * lda + slog * 8;
    const __bf16* pA1 = A  + (long)ar1 * lda + slog * 8;
    const __bf16* pB0 = Bt + (long)br0 * ldb + slog * 8;
    const __bf16* pB1 = Bt + (long)br1 * ldb + slog * 8;

    floatx4 acc[8][4] = {};

#define STAGE_A(RG, T, KH) { const int ko_ = (T) * 64 + (KH) * 32;            \
        gload_lds16(pA0 + ko_, &sA[RG][w * 1024]);                            \
        gload_lds16(pA1 + ko_, &sA[RG][w * 1024 + 512]); }
#define STAGE_B(RG, T, KH) { const int ko_ = (T) * 64 + (KH) * 32;            \
        gload_lds16(pB0 + ko_, &sB[RG][w * 1024]);                            \
        gload_lds16(pB1 + ko_, &sB[RG][w * 1024 + 512]); }

#define PHASE(MG, KK, RBUF, STAGE_STMT, DO_VM)                                \
    {                                                                         \
        bf16x8 af_[4], bv_[4];                                                \
        _Pragma("unroll")                                                     \
        for (int ii = 0; ii < 4; ++ii)                                        \
            af_[ii] = *reinterpret_cast<const bf16x8*>(                       \
                &sA[(RBUF) * 2 + (KK)][a_base + ((MG) * 4 + ii) * 512]);      \
        _Pragma("unroll")                                                     \
        for (int jj = 0; jj < 4; ++jj)                                        \
            bv_[jj] = *reinterpret_cast<const bf16x8*>(                       \
                &sB[(RBUF) * 2 + (KK)][b_base + jj * 512]);                   \
        STAGE_STMT;                                                           \
        __builtin_amdgcn_s_barrier();                                         \
        asm volatile("s_waitcnt lgkmcnt(0)" ::: "memory");                    \
        __builtin_amdgcn_sched_barrier(0);                                    \
        __builtin_amdgcn_s_setprio(1);                                        \
        _Pragma("unroll")                                                     \
        for (int ii = 0; ii < 4; ++ii)                                        \
            _Pragma("unroll")                                                 \
            for (int jj = 0; jj < 4; ++jj)                                    \
                acc[(MG) * 4 + ii][jj] =                                      \
                    __builtin_amdgcn_mfma_f32_16x16x32_bf16(                  \
                        af_[ii], bv_[jj], acc[(MG) * 4 + ii][jj], 0, 0, 0);   \
        __builtin_amdgcn_s_setprio(0);                                        \
        if (DO_VM) asm volatile("s_waitcnt vmcnt(8)" ::: "memory");           \
        __builtin_amdgcn_sched_barrier(0);                                    \
        __builtin_amdgcn_s_barrier();                                         \
    }

    const int NT    = K >> 6;     // K tiles of 64 (must be even)
    const int NITER = NT >> 1;

    // prologue: k0(t0), k1(t0), k0(t1) = 12 gloads; wait oldest 4 (k0(t0))
    STAGE_A(0, 0, 0); STAGE_B(0, 0, 0);
    STAGE_A(1, 0, 1); STAGE_B(1, 0, 1);
    STAGE_A(2, 1, 0); STAGE_B(2, 1, 0);
    asm volatile("s_waitcnt vmcnt(8)" ::: "memory");
    __builtin_amdgcn_s_barrier();

    for (int it = 0; it < NITER; ++it) {
        const int t1  = 2 * it + 1;
        const int tS2 = (2 * it + 2 < NT) ? 2 * it + 2 : NT - 1;
        const int tS3 = (2 * it + 3 < NT) ? 2 * it + 3 : NT - 1;
        PHASE(0, 0, 0, STAGE_A(3, t1, 1), 0)
        PHASE(1, 0, 0, STAGE_B(3, t1, 1), 1)
        PHASE(0, 1, 0, STAGE_A(0, tS2, 0), 0)
        PHASE(1, 1, 0, STAGE_B(0, tS2, 0), 1)
        PHASE(0, 0, 1, STAGE_A(1, tS2, 1), 0)
        PHASE(1, 0, 1, STAGE_B(1, tS2, 1), 1)
        PHASE(0, 1, 1, STAGE_A(2, tS3, 0), 0)
        PHASE(1, 1, 1, STAGE_B(2, tS3, 0), 1)
    }
#undef PHASE
#undef STAGE_A
#undef STAGE_B

    // epilogue: D frag (i,j): row = q*4+r, col = lr (verified C/D layout)
#pragma unroll
    for (int j = 0; j < 4; ++j) {
        const int n = n0 + wn * 64 + j * 16 + lr;
        float bi = 0.f, sc = 1.f;
        if (n < N) { bi = bias[n]; if (MODE == 0) sc = scale[n]; }
#pragma unroll
        for (int i = 0; i < 8; ++i) {
            const int mbase = m0 + wm * 128 + i * 16 + q * 4;
#pragma unroll
            for (int r = 0; r < 4; ++r) {
                const int m = mbase + r;
                if (m < M && n < N) {
                    float v = acc[i][j][r];
                    if (MODE == 0) {
                        v = (v + bi) * sc;
                        ((__bf16*)Cout)[(long)m * ldc + n] = (__bf16)v;
                    } else { // MODE 3
                        v = v + bi;
                        v = v > 0.f ? v : 0.f;
                        v += addx[(long)m * ldc + n];
                        ((float*)Cout)[(long)m * ldc + n] = v;
                    }
                }
            }
        }
    }
}

// ---------------------------------------------------------------------------
// 128x128-tile bf16 MFMA GEMM (kept for the batched small-M GEMMs 2 and 3).
// ---------------------------------------------------------------------------
template<int MODE>
__global__ __launch_bounds__(256) void gemm128(
    const __bf16* __restrict__ A,  int lda, long sAb,
    const __bf16* __restrict__ Bt, int ldb, long sBb,
    void* __restrict__ Cout, int ldc, long sCb,
    int M, int N, int K,
    const float* __restrict__ bias,
    const float* __restrict__ scale,
    const float* __restrict__ addx)
{
    const int z = blockIdx.z;
    const __bf16* Ab = A  + (long)z * sAb;
    const __bf16* Bb = Bt + (long)z * sBb;
    const int m0 = blockIdx.y * 128;
    const int n0 = blockIdx.x * 128;
    const int t  = threadIdx.x;
    const int w  = t >> 6;
    const int l  = t & 63;
    const int lr = l & 15;
    const int q  = l >> 4;

    __shared__ __align__(16) __bf16 sa[2][128 * 32];
    __shared__ __align__(16) __bf16 sb[2][128 * 32];

    floatx4 acc[4][4] = {};

    const int wm = (w & 1) * 64;
    const int wn = (w >> 1) * 64;

    const int srow = l >> 2;
    const int skc  = (l & 3) * 8;

    int arow0 = m0 + w * 16 + srow;        if (arow0 > M - 1) arow0 = M - 1;
    int arow1 = m0 + (w + 4) * 16 + srow;  if (arow1 > M - 1) arow1 = M - 1;
    int brow0 = n0 + w * 16 + srow;        if (brow0 > N - 1) brow0 = N - 1;
    int brow1 = n0 + (w + 4) * 16 + srow;  if (brow1 > N - 1) brow1 = N - 1;

    const __bf16* agp0 = Ab + (long)arow0 * lda + skc;
    const __bf16* agp1 = Ab + (long)arow1 * lda + skc;
    const __bf16* bgp0 = Bb + (long)brow0 * ldb + skc;
    const __bf16* bgp1 = Bb + (long)brow1 * ldb + skc;

    auto issue = [&](int buf, int k0) {
        gload_lds16(agp0 + k0, &sa[buf][(size_t)w * 512]);
        gload_lds16(agp1 + k0, &sa[buf][(size_t)(w + 4) * 512]);
        gload_lds16(bgp0 + k0, &sb[buf][(size_t)w * 512]);
        gload_lds16(bgp1 + k0, &sb[buf][(size_t)(w + 4) * 512]);
    };

    auto compute = [&](int buf) {
        bf16x8 af[4], bfv[4];
#pragma unroll
        for (int i = 0; i < 4; ++i)
            af[i] = *reinterpret_cast<const bf16x8*>(&sa[buf][(wm + i * 16 + lr) * 32 + q * 8]);
#pragma unroll
        for (int j = 0; j < 4; ++j)
            bfv[j] = *reinterpret_cast<const bf16x8*>(&sb[buf][(wn + j * 16 + lr) * 32 + q * 8]);
#pragma unroll
        for (int i = 0; i < 4; ++i)
#pragma unroll
            for (int j = 0; j < 4; ++j)
                acc[i][j] = __builtin_amdgcn_mfma_f32_16x16x32_bf16(af[i], bfv[j], acc[i][j], 0, 0, 0);
    };

    issue(0, 0);
    __syncthreads();
    for (int k0 = 0; k0 < K; k0 += 64) {
        issue(1, k0 + 32);
        compute(0);
        __syncthreads();
        if (k0 + 64 < K) issue(0, k0 + 64);
        compute(1);
        __syncthreads();
    }

#pragma unroll
    for (int i = 0; i < 4; ++i) {
        const int mbase = m0 + wm + i * 16 + q * 4;
#pragma unroll
        for (int j = 0; j < 4; ++j) {
            const int n = n0 + wn + j * 16 + lr;
#pragma unroll
            for (int r = 0; r < 4; ++r) {
                const int m = mbase + r;
                if (m < M && n < N) {
                    float v = acc[i][j][r];
                    if (MODE == 0) {
                        v = (v + bias[n]) * scale[n];
                        ((__bf16*)Cout)[(long)z * sCb + (long)m * ldc + n] = (__bf16)v;
                    } else if (MODE == 1) {
                        ((__bf16*)Cout)[(long)z * sCb + (long)m * ldc + n] = (__bf16)v;
                    } else {
                        v = v + bias[n];
                        v = v > 0.f ? v : 0.f;
                        v += addx[(long)m * ldc + n];
                        ((float*)Cout)[(long)m * ldc + n] = v;
                    }
                }
            }
        }
    }
}

// ---------------------------------------------------------------------------
__global__ __launch_bounds__(256) void convert_x(const float4* __restrict__ x4,
                                                 __bf16* __restrict__ xb, int n4)
{
    int i = blockIdx.x * 256 + threadIdx.x;
    int stride = gridDim.x * 256;
    for (; i < n4; i += stride) {
        float4 v = x4[i];
        bf16x4 o;
        o[0] = (__bf16)v.x; o[1] = (__bf16)v.y; o[2] = (__bf16)v.z; o[3] = (__bf16)v.w;
        *reinterpret_cast<bf16x4*>(xb + 4 * (long)i) = o;
    }
}

// ---------------------------------------------------------------------------
__global__ __launch_bounds__(256) void prep_weights(
    const float* __restrict__ Wq, const float* __restrict__ bq,
    const float* __restrict__ Wk, const float* __restrict__ bk,
    const float* __restrict__ Wg,
    __bf16* __restrict__ WqkT, __bf16* __restrict__ WgT,
    float* __restrict__ biasqk, float* __restrict__ scaleqk)
{
    int blk = blockIdx.x, t = threadIdx.x;
    if (blk < 384) {
        int n = blk;
        const float* W = (n < RR) ? Wq : Wk;
        int nn = (n < RR) ? n : n - RR;
        for (int k = t; k < CC; k += 256)
            WqkT[(long)n * CC + k] = (__bf16)W[(long)k * RR + nn];
        if (blk == 0) {
            for (int i = t; i < 384; i += 256) {
                biasqk[i]  = (i < RR) ? bq[i] : bk[i - RR];
                scaleqk[i] = (i < RR) ? rsqrtf((float)RR) : 1.0f;
            }
        }
    } else {
        int n = blk - 384;
        for (int k = t; k < CC; k += 256)
            WgT[(long)n * CC + k] = (__bf16)Wg[(long)k * CC + n];
    }
}

// ---------------------------------------------------------------------------
__global__ __launch_bounds__(256) void transpose_x(const __bf16* __restrict__ xb,
                                                   __bf16* __restrict__ xbT)
{
    const int c0 = (blockIdx.x % 12) * 64;
    const int b  = blockIdx.x / 12;
    __shared__ __bf16 lds[64 * 194];
    const int t = threadIdx.x;

    for (int i = 0; i < 45; ++i) {
        int idx = i * 256 + t;
        int m = idx >> 6, c = idx & 63;
        lds[c * 194 + m] = xb[((long)(b * NN + m)) * CC + c0 + c];
    }
    __syncthreads();
    for (int j = 0; j < 48; ++j) {
        int idx = j * 256 + t;
        int c = idx / KPAD, m = idx % KPAD;
        __bf16 v = (m < NN) ? lds[c * 194 + m] : (__bf16)0.0f;
        xbT[((long)(b * CC + c0 + c)) * KPAD + m] = v;
    }
}

// ---------------------------------------------------------------------------
__global__ __launch_bounds__(256) void softmax_combine(
    const __bf16* __restrict__ S, const float* __restrict__ A_phys,
    const float* __restrict__ alpha, __bf16* __restrict__ Acomb)
{
    const int w = threadIdx.x >> 6, l = threadIdx.x & 63;
    const long row = (long)blockIdx.x * 4 + w;
    const int b = (int)(row / NN), n = (int)(row % NN);
    const __bf16* Srow = S + ((long)b * NN + n) * NN;

    float v[3];
#pragma unroll
    for (int i = 0; i < 3; ++i) {
        int m = l + 64 * i;
        v[i] = (m < NN) ? (float)Srow[m] : -1e30f;
    }
    float mx = fmaxf(fmaxf(v[0], v[1]), v[2]);
    for (int off = 32; off; off >>= 1) mx = fmaxf(mx, __shfl_xor(mx, off, 64));

    float e[3], sum = 0.f;
#pragma unroll
    for (int i = 0; i < 3; ++i) {
        int m = l + 64 * i;
        e[i] = (m < NN) ? expf(v[i] - mx) : 0.f;
        sum += e[i];
    }
    for (int off = 32; off; off >>= 1) sum += __shfl_xor(sum, off, 64);

    const float a   = 1.f / (1.f + expf(-alpha[0]));
    const float inv = (1.f - a) / sum;
    __bf16* Orow = Acomb + ((long)b * NN + n) * KPAD;
#pragma unroll
    for (int i = 0; i < 3; ++i) {
        int m = l + 64 * i;
        if (m < KPAD) {
            float o = (m < NN) ? (a * A_phys[n * NN + m] + e[i] * inv) : 0.f;
            Orow[m] = (__bf16)o;
        }
    }
}

// ---------------------------------------------------------------------------
__global__ __launch_bounds__(256) void ln_kernel(float* __restrict__ out,
                                                 const float* __restrict__ gamma,
                                                 const float* __restrict__ beta)
{
    float* p = out + (long)blockIdx.x * CC;
    const int t = threadIdx.x, w = t >> 6, l = t & 63;
    float h[3], s = 0.f, s2 = 0.f;
#pragma unroll
    for (int i = 0; i < 3; ++i) {
        h[i] = p[t + 256 * i];
        s += h[i]; s2 += h[i] * h[i];
    }
    for (int off = 32; off; off >>= 1) { s += __shfl_xor(s, off, 64); s2 += __shfl_xor(s2, off, 64); }
    __shared__ float ps[4], ps2[4];
    if (l == 0) { ps[w] = s; ps2[w] = s2; }
    __syncthreads();
    s  = ps[0] + ps[1] + ps[2] + ps[3];
    s2 = ps2[0] + ps2[1] + ps2[2] + ps2[3];
    const float mu  = s * (1.f / CC);
    const float var = s2 * (1.f / CC) - mu * mu;
    const float rs  = rsqrtf(var + 1e-5f);
#pragma unroll
    for (int i = 0; i < 3; ++i) {
        int c = t + 256 * i;
        p[c] = (h[i] - mu) * rs * gamma[c] + beta[c];
    }
}

// ---------------------------------------------------------------------------
extern "C" void kernel_launch(void* const* d_in, const int* in_sizes, int n_in,
                              void* d_out, int out_size, void* d_ws, size_t ws_size,
                              hipStream_t stream)
{
    const float* x      = (const float*)d_in[0];
    const float* Wq     = (const float*)d_in[1];
    const float* bq     = (const float*)d_in[2];
    const float* Wk     = (const float*)d_in[3];
    const float* bk     = (const float*)d_in[4];
    const float* Wg     = (const float*)d_in[5];
    const float* bg     = (const float*)d_in[6];
    const float* gamma  = (const float*)d_in[7];
    const float* beta   = (const float*)d_in[8];
    const float* alpha  = (const float*)d_in[9];
    const float* A_phys = (const float*)d_in[10];

    // allow 128 KB dynamic LDS for gemm256 (one-time)
    static bool attr_done = false;
    if (!attr_done) {
        auto k0 = gemm256<0>;
        auto k3 = gemm256<3>;
        hipFuncSetAttribute((const void*)k0, hipFuncAttributeMaxDynamicSharedMemorySize, 131072);
        hipFuncSetAttribute((const void*)k3, hipFuncAttributeMaxDynamicSharedMemorySize, 131072);
        attr_done = true;
    }

    // ---- workspace carve (bytes). Lifetime aliases: z over xb, Acomb over QK.
    char* w = (char*)d_ws;
    __bf16* xb    = (__bf16*)(w + 0);                       // 70,778,880  (also z)
    __bf16* zbuf  = xb;
    __bf16* xbT   = (__bf16*)(w + 70778880);                // 75,497,472
    __bf16* QK    = (__bf16*)(w + 146276352);               // 35,389,440  (also Acomb)
    __bf16* Acomb = QK;
    __bf16* S     = (__bf16*)(w + 181665792);               // 16,588,800
    __bf16* WqkT  = (__bf16*)(w + 198254592);               //    589,824
    __bf16* WgT   = (__bf16*)(w + 198844416);               //  1,179,648
    float*  biasqk  = (float*)(w + 200024064);              //      1,536
    float*  scaleqk = (float*)(w + 200025600);              //      1,536

    // 1) conversions / transposes
    convert_x<<<4096, 256, 0, stream>>>((const float4*)x, xb, MROWS * CC / 4);
    prep_weights<<<384 + CC, 256, 0, stream>>>(Wq, bq, Wk, bk, Wg, WqkT, WgT, biasqk, scaleqk);
    transpose_x<<<BB * 12, 256, 0, stream>>>(xb, xbT);

    // 2) GEMM1: [46080,768] @ WqkT^T -> QK [46080,384] bf16 (Q scaled by 1/sqrt(R))
    //    256^2 8-phase kernel; N=384 handled via B-row clamp + store guard.
    gemm256<0><<<dim3(2, MROWS / 256, 1), 512, 131072, stream>>>(
        xb, CC, WqkT, CC, QK, 384,
        MROWS, 384, CC, biasqk, scaleqk, nullptr);

    // 3) GEMM2 (batched): S[b] = Q[b] (180x192) @ K[b]^T -> [180,180] bf16
    gemm128<1><<<dim3(2, 2, BB), 256, 0, stream>>>(
        QK, 384, (long)NN * 384, QK + RR, 384, (long)NN * 384,
        S, NN, (long)NN * NN,
        NN, NN, RR, nullptr, nullptr, nullptr);

    // 4) softmax + alpha combine -> Acomb [B][180][192] bf16 (overwrites QK region)
    softmax_combine<<<MROWS / 4, 256, 0, stream>>>(S, A_phys, alpha, Acomb);

    // 5) GEMM3 (batched): z[b] = Acomb[b] (180x192) @ xbT[b]^T (192x768) -> bf16
    gemm128<1><<<dim3(CC / 128, 2, BB), 256, 0, stream>>>(
        Acomb, KPAD, (long)NN * KPAD, xbT, KPAD, (long)CC * KPAD,
        zbuf, CC, (long)NN * CC,
        NN, CC, KPAD, nullptr, nullptr, nullptr);

    // 6) GEMM4: h = x + relu(z @ Wg + bg) -> d_out f32 [46080,768]
    gemm256<3><<<dim3(CC / 256, MROWS / 256, 1), 512, 131072, stream>>>(
        zbuf, CC, WgT, CC, d_out, CC,
        MROWS, CC, CC, bg, nullptr, x);

    // 7) in-place LayerNorm
    ln_kernel<<<MROWS, 256, 0, stream>>>((float*)d_out, gamma, beta);
}

// Round 2
// 667.176 us; speedup vs baseline: 1.1506x; 1.1506x over previous
//
#include <hip/hip_runtime.h>
#include <hip/hip_bf16.h>
#include <math.h>
#include <stdint.h>

// Problem constants
#define BB   256
#define NN   180
#define CC   768
#define RR   192
#define MROWS (BB*NN)      // 46080 flat rows
#define KPAD 192           // node-dim padded to 192 for GEMM3 K

typedef __attribute__((ext_vector_type(8))) __bf16 bf16x8;
typedef __attribute__((ext_vector_type(4))) __bf16 bf16x4;
typedef __attribute__((ext_vector_type(4))) float  floatx4;

// async global->LDS, 16 B per lane. LDS dest is wave-uniform base + lane*16.
__device__ __forceinline__ void gload_lds16(const __bf16* g, __bf16* lds)
{
    __builtin_amdgcn_global_load_lds(
        (const __attribute__((address_space(1))) void*)(uintptr_t)(const void*)g,
        (__attribute__((address_space(3))) void*)(uintptr_t)(void*)lds,
        16, 0, 0);
}

// ---------------------------------------------------------------------------
// 128x128-tile bf16 MFMA GEMM, B transposed (Bt[n][k]).
// 4 waves, each computes a 64x64 patch (4x4 grid of 16x16x32 MFMA).
// K-loop double-buffered; LDS-DMA for chunk k+1 issued BEFORE compute on k.
// R2 additions (proven mechanisms from R1's gemm256):
//  - T2 LDS XOR-swizzle: phys 16B-slot = logical ^ ((row>>1)&3), applied on
//    the per-lane GLOBAL source addr (LDS dest stays linear, rule #21) and
//    identically on the ds_read side. R1 measured: bank conflicts 6.6M -> 0.
//  - T1 bijective XCD swizzle (m204): consecutive lin blocks (which share an
//    A-panel across n-tiles) land on the same XCD L2 -> A fetched ~1x not 6x.
// MODE 0: out bf16, val=(acc+bias[n])*scale[n]            (Q/K projection)
// MODE 1: out bf16, raw                                    (scores / z)
// MODE 3: out f32,  val=relu(acc+bias[n]) + addx[m*ldc+n]  (z@Wg + residual)
// ---------------------------------------------------------------------------
template<int MODE>
__global__ __launch_bounds__(256) void gemm128(
    const __bf16* __restrict__ A,  int lda, long sAb,
    const __bf16* __restrict__ Bt, int ldb, long sBb,
    void* __restrict__ Cout, int ldc, long sCb,
    int M, int N, int K,
    const float* __restrict__ bias,
    const float* __restrict__ scale,
    const float* __restrict__ addx)
{
    const int z = blockIdx.z;
    const __bf16* Ab = A  + (long)z * sAb;
    const __bf16* Bb = Bt + (long)z * sBb;

    // T1: bijective XCD chunking over the xy grid (per batch slice)
    const int nwg = gridDim.x * gridDim.y;
    const int lin = blockIdx.y * gridDim.x + blockIdx.x;
    const int qd = nwg >> 3, rr = nwg & 7, xc = lin & 7, oo = lin >> 3;
    const int wg = (xc < rr ? xc * (qd + 1) : rr * (qd + 1) + (xc - rr) * qd) + oo;
    const int m0 = (wg / gridDim.x) * 128;
    const int n0 = (wg % gridDim.x) * 128;

    const int t  = threadIdx.x;
    const int w  = t >> 6;
    const int l  = t & 63;
    const int lr = l & 15;
    const int q  = l >> 4;
    const int xr = (lr >> 1) & 3;          // read-side swizzle factor

    __shared__ __align__(16) __bf16 sa[2][128 * 32];   // 2 x 8 KB
    __shared__ __align__(16) __bf16 sb[2][128 * 32];   // 2 x 8 KB

    floatx4 acc[4][4] = {};

    const int wm = (w & 1) * 64;     // wave's m-offset within tile
    const int wn = (w >> 1) * 64;    // wave's n-offset within tile

    // staging lane map: chunk = 16 rows x 32 k (1024 B); lane l -> row l>>2,
    // phys slot l&3 holds logical slot (l&3)^((l>>3)&3)  (source pre-swizzle)
    const int srow = l >> 2;
    const int skc  = ((l & 3) ^ ((l >> 3) & 3)) * 8;

    int arow0 = m0 + w * 16 + srow;        if (arow0 > M - 1) arow0 = M - 1;
    int arow1 = m0 + (w + 4) * 16 + srow;  if (arow1 > M - 1) arow1 = M - 1;
    int brow0 = n0 + w * 16 + srow;        if (brow0 > N - 1) brow0 = N - 1;
    int brow1 = n0 + (w + 4) * 16 + srow;  if (brow1 > N - 1) brow1 = N - 1;

    const __bf16* agp0 = Ab + (long)arow0 * lda + skc;
    const __bf16* agp1 = Ab + (long)arow1 * lda + skc;
    const __bf16* bgp0 = Bb + (long)brow0 * ldb + skc;
    const __bf16* bgp1 = Bb + (long)brow1 * ldb + skc;

    auto issue = [&](int buf, int k0) {
        gload_lds16(agp0 + k0, &sa[buf][(size_t)w * 512]);
        gload_lds16(agp1 + k0, &sa[buf][(size_t)(w + 4) * 512]);
        gload_lds16(bgp0 + k0, &sb[buf][(size_t)w * 512]);
        gload_lds16(bgp1 + k0, &sb[buf][(size_t)(w + 4) * 512]);
    };

    auto compute = [&](int buf) {
        bf16x8 af[4], bfv[4];
#pragma unroll
        for (int i = 0; i < 4; ++i)
            af[i] = *reinterpret_cast<const bf16x8*>(
                &sa[buf][(wm + i * 16 + lr) * 32 + ((q ^ xr) * 8)]);
#pragma unroll
        for (int j = 0; j < 4; ++j)
            bfv[j] = *reinterpret_cast<const bf16x8*>(
                &sb[buf][(wn + j * 16 + lr) * 32 + ((q ^ xr) * 8)]);
#pragma unroll
        for (int i = 0; i < 4; ++i)
#pragma unroll
            for (int j = 0; j < 4; ++j)
                acc[i][j] = __builtin_amdgcn_mfma_f32_16x16x32_bf16(af[i], bfv[j], acc[i][j], 0, 0, 0);
    };

    issue(0, 0);
    __syncthreads();                       // drain prologue loads (no overlap, once)
    for (int k0 = 0; k0 < K; k0 += 64) {
        issue(1, k0 + 32);                 // in flight during compute(0)
        compute(0);
        __syncthreads();                   // all read buf0; buf1 DMA drained post-compute
        if (k0 + 64 < K) issue(0, k0 + 64);
        compute(1);
        __syncthreads();
    }

    // epilogue: D subtile (i,j): row = q*4+r, col = lr
#pragma unroll
    for (int i = 0; i < 4; ++i) {
        const int mbase = m0 + wm + i * 16 + q * 4;
#pragma unroll
        for (int j = 0; j < 4; ++j) {
            const int n = n0 + wn + j * 16 + lr;
#pragma unroll
            for (int r = 0; r < 4; ++r) {
                const int m = mbase + r;
                if (m < M && n < N) {
                    float v = acc[i][j][r];
                    if (MODE == 0) {
                        v = (v + bias[n]) * scale[n];
                        ((__bf16*)Cout)[(long)z * sCb + (long)m * ldc + n] = (__bf16)v;
                    } else if (MODE == 1) {
                        ((__bf16*)Cout)[(long)z * sCb + (long)m * ldc + n] = (__bf16)v;
                    } else { // MODE 3
                        v = v + bias[n];
                        v = v > 0.f ? v : 0.f;
                        v += addx[(long)m * ldc + n];
                        ((float*)Cout)[(long)m * ldc + n] = v;
                    }
                }
            }
        }
    }
}

// ---------------------------------------------------------------------------
// Fused: x (f32) -> xb (bf16)  AND  xbT[b][c][m] (m padded to 192) transpose.
// Saves the 71 MB xb re-read of the former separate transpose pass.
// One block per (b, 64-col slab): reads x once (float4), writes xb + xbT.
// ---------------------------------------------------------------------------
__global__ __launch_bounds__(256) void convert_transpose_x(
    const float* __restrict__ x, __bf16* __restrict__ xb, __bf16* __restrict__ xbT)
{
    const int c0 = (blockIdx.x % 12) * 64;
    const int b  = blockIdx.x / 12;
    __shared__ __bf16 lds[64 * 194];
    const int t = threadIdx.x;

    // 180 rows x 16 float4 = 2880 vec loads per block
    for (int i = 0; i < 12; ++i) {
        int idx = i * 256 + t;
        if (idx < 2880) {
            int m = idx >> 4, c4 = idx & 15;
            float4 v = *reinterpret_cast<const float4*>(
                &x[((long)(b * NN + m)) * CC + c0 + c4 * 4]);
            bf16x4 o;
            o[0] = (__bf16)v.x; o[1] = (__bf16)v.y;
            o[2] = (__bf16)v.z; o[3] = (__bf16)v.w;
            *reinterpret_cast<bf16x4*>(&xb[((long)(b * NN + m)) * CC + c0 + c4 * 4]) = o;
            lds[(c4 * 4 + 0) * 194 + m] = o[0];
            lds[(c4 * 4 + 1) * 194 + m] = o[1];
            lds[(c4 * 4 + 2) * 194 + m] = o[2];
            lds[(c4 * 4 + 3) * 194 + m] = o[3];
        }
    }
    __syncthreads();
    for (int j = 0; j < 48; ++j) {
        int idx = j * 256 + t;
        int c = idx / KPAD, m = idx % KPAD;
        __bf16 v = (m < NN) ? lds[c * 194 + m] : (__bf16)0.0f;
        xbT[((long)(b * CC + c0 + c)) * KPAD + m] = v;
    }
}

// ---------------------------------------------------------------------------
// Weights: WqkT[384][768] = [Wq|Wk]^T (bf16), WgT[768][768] = Wg^T (bf16),
// plus combined bias[384] and per-column scale[384] (1/sqrt(R) on Q cols).
// ---------------------------------------------------------------------------
__global__ __launch_bounds__(256) void prep_weights(
    const float* __restrict__ Wq, const float* __restrict__ bq,
    const float* __restrict__ Wk, const float* __restrict__ bk,
    const float* __restrict__ Wg,
    __bf16* __restrict__ WqkT, __bf16* __restrict__ WgT,
    float* __restrict__ biasqk, float* __restrict__ scaleqk)
{
    int blk = blockIdx.x, t = threadIdx.x;
    if (blk < 384) {
        int n = blk;
        const float* W = (n < RR) ? Wq : Wk;
        int nn = (n < RR) ? n : n - RR;
        for (int k = t; k < CC; k += 256)
            WqkT[(long)n * CC + k] = (__bf16)W[(long)k * RR + nn];
        if (blk == 0) {
            for (int i = t; i < 384; i += 256) {
                biasqk[i]  = (i < RR) ? bq[i] : bk[i - RR];
                scaleqk[i] = (i < RR) ? rsqrtf((float)RR) : 1.0f;
            }
        }
    } else {
        int n = blk - 384;
        for (int k = t; k < CC; k += 256)
            WgT[(long)n * CC + k] = (__bf16)Wg[(long)k * CC + n];
    }
}

// ---------------------------------------------------------------------------
// Row softmax of S (bf16, [B][180][180]) + combine with alpha/A_phys,
// write A_comb bf16 [B][180][192] (K-padded with zeros). One wave per row.
// ---------------------------------------------------------------------------
__global__ __launch_bounds__(256) void softmax_combine(
    const __bf16* __restrict__ S, const float* __restrict__ A_phys,
    const float* __restrict__ alpha, __bf16* __restrict__ Acomb)
{
    const int w = threadIdx.x >> 6, l = threadIdx.x & 63;
    const long row = (long)blockIdx.x * 4 + w;
    const int b = (int)(row / NN), n = (int)(row % NN);
    const __bf16* Srow = S + ((long)b * NN + n) * NN;

    float v[3];
#pragma unroll
    for (int i = 0; i < 3; ++i) {
        int m = l + 64 * i;
        v[i] = (m < NN) ? (float)Srow[m] : -1e30f;
    }
    float mx = fmaxf(fmaxf(v[0], v[1]), v[2]);
    for (int off = 32; off; off >>= 1) mx = fmaxf(mx, __shfl_xor(mx, off, 64));

    float e[3], sum = 0.f;
#pragma unroll
    for (int i = 0; i < 3; ++i) {
        int m = l + 64 * i;
        e[i] = (m < NN) ? expf(v[i] - mx) : 0.f;
        sum += e[i];
    }
    for (int off = 32; off; off >>= 1) sum += __shfl_xor(sum, off, 64);

    const float a   = 1.f / (1.f + expf(-alpha[0]));
    const float inv = (1.f - a) / sum;
    __bf16* Orow = Acomb + ((long)b * NN + n) * KPAD;
#pragma unroll
    for (int i = 0; i < 3; ++i) {
        int m = l + 64 * i;
        if (m < KPAD) {
            float o = (m < NN) ? (a * A_phys[n * NN + m] + e[i] * inv) : 0.f;
            Orow[m] = (__bf16)o;
        }
    }
}

// ---------------------------------------------------------------------------
// In-place LayerNorm over channel dim; one block per row of 768.
// ---------------------------------------------------------------------------
__global__ __launch_bounds__(256) void ln_kernel(float* __restrict__ out,
                                                 const float* __restrict__ gamma,
                                                 const float* __restrict__ beta)
{
    float* p = out + (long)blockIdx.x * CC;
    const int t = threadIdx.x, w = t >> 6, l = t & 63;
    float h[3], s = 0.f, s2 = 0.f;
#pragma unroll
    for (int i = 0; i < 3; ++i) {
        h[i] = p[t + 256 * i];
        s += h[i]; s2 += h[i] * h[i];
    }
    for (int off = 32; off; off >>= 1) { s += __shfl_xor(s, off, 64); s2 += __shfl_xor(s2, off, 64); }
    __shared__ float ps[4], ps2[4];
    if (l == 0) { ps[w] = s; ps2[w] = s2; }
    __syncthreads();
    s  = ps[0] + ps[1] + ps[2] + ps[3];
    s2 = ps2[0] + ps2[1] + ps2[2] + ps2[3];
    const float mu  = s * (1.f / CC);
    const float var = s2 * (1.f / CC) - mu * mu;
    const float rs  = rsqrtf(var + 1e-5f);
#pragma unroll
    for (int i = 0; i < 3; ++i) {
        int c = t + 256 * i;
        p[c] = (h[i] - mu) * rs * gamma[c] + beta[c];
    }
}

// ---------------------------------------------------------------------------
extern "C" void kernel_launch(void* const* d_in, const int* in_sizes, int n_in,
                              void* d_out, int out_size, void* d_ws, size_t ws_size,
                              hipStream_t stream)
{
    const float* x      = (const float*)d_in[0];
    const float* Wq     = (const float*)d_in[1];
    const float* bq     = (const float*)d_in[2];
    const float* Wk     = (const float*)d_in[3];
    const float* bk     = (const float*)d_in[4];
    const float* Wg     = (const float*)d_in[5];
    const float* bg     = (const float*)d_in[6];
    const float* gamma  = (const float*)d_in[7];
    const float* beta   = (const float*)d_in[8];
    const float* alpha  = (const float*)d_in[9];
    const float* A_phys = (const float*)d_in[10];

    // ---- workspace carve (bytes). Lifetime aliases: z over xb, Acomb over QK.
    char* w = (char*)d_ws;
    __bf16* xb    = (__bf16*)(w + 0);                       // 70,778,880  (also z)
    __bf16* zbuf  = xb;
    __bf16* xbT   = (__bf16*)(w + 70778880);                // 75,497,472
    __bf16* QK    = (__bf16*)(w + 146276352);               // 35,389,440  (also Acomb)
    __bf16* Acomb = QK;
    __bf16* S     = (__bf16*)(w + 181665792);               // 16,588,800
    __bf16* WqkT  = (__bf16*)(w + 198254592);               //    589,824
    __bf16* WgT   = (__bf16*)(w + 198844416);               //  1,179,648
    float*  biasqk  = (float*)(w + 200024064);              //      1,536
    float*  scaleqk = (float*)(w + 200025600);              //      1,536

    // 1) weight prep + fused x convert/transpose
    prep_weights<<<384 + CC, 256, 0, stream>>>(Wq, bq, Wk, bk, Wg, WqkT, WgT, biasqk, scaleqk);
    convert_transpose_x<<<BB * 12, 256, 0, stream>>>(x, xb, xbT);

    // 2) GEMM1: [46080,768] @ WqkT^T -> QK [46080,384] bf16 (Q scaled by 1/sqrt(R))
    gemm128<0><<<dim3(384 / 128, MROWS / 128, 1), 256, 0, stream>>>(
        xb, CC, 0L, WqkT, CC, 0L, QK, 384, 0L,
        MROWS, 384, CC, biasqk, scaleqk, nullptr);

    // 3) GEMM2 (batched): S[b] = Q[b] (180x192) @ K[b]^T -> [180,180] bf16
    gemm128<1><<<dim3(2, 2, BB), 256, 0, stream>>>(
        QK, 384, (long)NN * 384, QK + RR, 384, (long)NN * 384,
        S, NN, (long)NN * NN,
        NN, NN, RR, nullptr, nullptr, nullptr);

    // 4) softmax + alpha combine -> Acomb [B][180][192] bf16 (overwrites QK region)
    softmax_combine<<<MROWS / 4, 256, 0, stream>>>(S, A_phys, alpha, Acomb);

    // 5) GEMM3 (batched): z[b] = Acomb[b] (180x192) @ xbT[b]^T (192x768) -> bf16
    gemm128<1><<<dim3(CC / 128, 2, BB), 256, 0, stream>>>(
        Acomb, KPAD, (long)NN * KPAD, xbT, KPAD, (long)CC * KPAD,
        zbuf, CC, (long)NN * CC,
        NN, CC, KPAD, nullptr, nullptr, nullptr);

    // 6) GEMM4: h = x + relu(z @ Wg + bg) -> d_out f32 [46080,768]
    gemm128<3><<<dim3(CC / 128, MROWS / 128, 1), 256, 0, stream>>>(
        zbuf, CC, 0L, WgT, CC, 0L, d_out, CC, 0L,
        MROWS, CC, CC, bg, nullptr, x);

    // 7) in-place LayerNorm
    ln_kernel<<<MROWS, 256, 0, stream>>>((float*)d_out, gamma, beta);
}

// Round 3
// 666.492 us; speedup vs baseline: 1.1518x; 1.0010x over previous
//
#include <hip/hip_runtime.h>
#include <hip/hip_bf16.h>
#include <math.h>
#include <stdint.h>

// Problem constants
#define BB   256
#define NN   180
#define CC   768
#define RR   192
#define MROWS (BB*NN)      // 46080 flat rows
#define KPAD 192           // node-dim padded to 192 for GEMM3 K

typedef __attribute__((ext_vector_type(8))) __bf16 bf16x8;
typedef __attribute__((ext_vector_type(4))) __bf16 bf16x4;
typedef __attribute__((ext_vector_type(4))) float  floatx4;

// async global->LDS, 16 B per lane. LDS dest is wave-uniform base + lane*16.
__device__ __forceinline__ void gload_lds16(const __bf16* g, __bf16* lds)
{
    __builtin_amdgcn_global_load_lds(
        (const __attribute__((address_space(1))) void*)(uintptr_t)(const void*)g,
        (__attribute__((address_space(3))) void*)(uintptr_t)(void*)lds,
        16, 0, 0);
}

// ---------------------------------------------------------------------------
// 128x128-tile bf16 MFMA GEMM, B transposed (Bt[n][k]).
// 4 waves, each computes a 64x64 patch (4x4 grid of 16x16x32 MFMA).
// R3: K-loop is a 3-slot LDS ring with COUNTED vmcnt (T4) — chunk c+2's
// loads are issued at the top of epoch c; end-of-epoch wait is vmcnt(4)
// (slot c+1 ready, newest 4 loads stay in flight). Never drains to 0 in
// the loop -> each chunk's loads get ~2 compute-epochs of latency cover
// instead of ~77 cyc. Raw s_barrier + sched_barrier fencing (rules #18/#21).
// R2 mechanisms kept: T2 source-preswizzle LDS XOR (bank conflicts = 0),
// T1 bijective XCD swizzle (A-panel L2 reuse, FETCH 284->118 MB).
// MODE 0: out bf16, val=(acc+bias[n])*scale[n]            (Q/K projection)
// MODE 1: out bf16, raw                                    (scores / z)
// MODE 3: out f32,  val=relu(acc+bias[n]) + addx[m*ldc+n]  (z@Wg + residual)
// ---------------------------------------------------------------------------
template<int MODE>
__global__ __launch_bounds__(256) void gemm128(
    const __bf16* __restrict__ A,  int lda, long sAb,
    const __bf16* __restrict__ Bt, int ldb, long sBb,
    void* __restrict__ Cout, int ldc, long sCb,
    int M, int N, int K,
    const float* __restrict__ bias,
    const float* __restrict__ scale,
    const float* __restrict__ addx)
{
    const int z = blockIdx.z;
    const __bf16* Ab = A  + (long)z * sAb;
    const __bf16* Bb = Bt + (long)z * sBb;

    // T1: bijective XCD chunking over the xy grid (per batch slice)
    const int nwg = gridDim.x * gridDim.y;
    const int lin = blockIdx.y * gridDim.x + blockIdx.x;
    const int qd = nwg >> 3, rr = nwg & 7, xc = lin & 7, oo = lin >> 3;
    const int wg = (xc < rr ? xc * (qd + 1) : rr * (qd + 1) + (xc - rr) * qd) + oo;
    const int m0 = (wg / gridDim.x) * 128;
    const int n0 = (wg % gridDim.x) * 128;

    const int t  = threadIdx.x;
    const int w  = t >> 6;
    const int l  = t & 63;
    const int lr = l & 15;
    const int q  = l >> 4;
    const int xr = (lr >> 1) & 3;          // read-side swizzle factor

    __shared__ __align__(16) __bf16 sa[3][128 * 32];   // 3 x 8 KB ring
    __shared__ __align__(16) __bf16 sb[3][128 * 32];   // 3 x 8 KB ring

    floatx4 acc[4][4] = {};

    const int wm = (w & 1) * 64;     // wave's m-offset within tile
    const int wn = (w >> 1) * 64;    // wave's n-offset within tile

    // staging lane map: chunk = 16 rows x 32 k (1024 B); lane l -> row l>>2,
    // phys slot l&3 holds logical slot (l&3)^((l>>3)&3)  (source pre-swizzle)
    const int srow = l >> 2;
    const int skc  = ((l & 3) ^ ((l >> 3) & 3)) * 8;

    int arow0 = m0 + w * 16 + srow;        if (arow0 > M - 1) arow0 = M - 1;
    int arow1 = m0 + (w + 4) * 16 + srow;  if (arow1 > M - 1) arow1 = M - 1;
    int brow0 = n0 + w * 16 + srow;        if (brow0 > N - 1) brow0 = N - 1;
    int brow1 = n0 + (w + 4) * 16 + srow;  if (brow1 > N - 1) brow1 = N - 1;

    const __bf16* agp0 = Ab + (long)arow0 * lda + skc;
    const __bf16* agp1 = Ab + (long)arow1 * lda + skc;
    const __bf16* bgp0 = Bb + (long)brow0 * ldb + skc;
    const __bf16* bgp1 = Bb + (long)brow1 * ldb + skc;

    // issue chunk cc (32 k-elems) into ring slot
    auto issue = [&](int slot, int cc) {
        const int k0 = cc * 32;
        gload_lds16(agp0 + k0, &sa[slot][(size_t)w * 512]);
        gload_lds16(agp1 + k0, &sa[slot][(size_t)(w + 4) * 512]);
        gload_lds16(bgp0 + k0, &sb[slot][(size_t)w * 512]);
        gload_lds16(bgp1 + k0, &sb[slot][(size_t)(w + 4) * 512]);
    };

    auto compute = [&](int slot) {
        bf16x8 af[4], bfv[4];
#pragma unroll
        for (int i = 0; i < 4; ++i)
            af[i] = *reinterpret_cast<const bf16x8*>(
                &sa[slot][(wm + i * 16 + lr) * 32 + ((q ^ xr) * 8)]);
#pragma unroll
        for (int j = 0; j < 4; ++j)
            bfv[j] = *reinterpret_cast<const bf16x8*>(
                &sb[slot][(wn + j * 16 + lr) * 32 + ((q ^ xr) * 8)]);
#pragma unroll
        for (int i = 0; i < 4; ++i)
#pragma unroll
            for (int j = 0; j < 4; ++j)
                acc[i][j] = __builtin_amdgcn_mfma_f32_16x16x32_bf16(af[i], bfv[j], acc[i][j], 0, 0, 0);
    };

    const int NC = K >> 5;   // 32-k chunks: 24 (K=768) or 6 (K=192)

    // prologue: slots 0,1 in flight; wait for slot 0 only (vmcnt(4))
    issue(0, 0);
    issue(1, 1);
    asm volatile("s_waitcnt vmcnt(4)" ::: "memory");
    __builtin_amdgcn_sched_barrier(0);
    __builtin_amdgcn_s_barrier();
    __builtin_amdgcn_sched_barrier(0);

#pragma unroll 3
    for (int c = 0; c < NC; ++c) {
        const int cs = c % 3;            // compute slot
        if (c + 2 < NC) issue((c + 2) % 3, c + 2);
        compute(cs);
        if (c + 1 < NC) {
            // next epoch reads slot c+1: wait until only the newest 4 loads
            // (slot c+2, if issued) remain outstanding
            if (c + 2 < NC) asm volatile("s_waitcnt vmcnt(4)" ::: "memory");
            else            asm volatile("s_waitcnt vmcnt(0)" ::: "memory");
            __builtin_amdgcn_sched_barrier(0);
            __builtin_amdgcn_s_barrier();
            __builtin_amdgcn_sched_barrier(0);
        }
    }

    // epilogue: D subtile (i,j): row = q*4+r, col = lr
#pragma unroll
    for (int i = 0; i < 4; ++i) {
        const int mbase = m0 + wm + i * 16 + q * 4;
#pragma unroll
        for (int j = 0; j < 4; ++j) {
            const int n = n0 + wn + j * 16 + lr;
#pragma unroll
            for (int r = 0; r < 4; ++r) {
                const int m = mbase + r;
                if (m < M && n < N) {
                    float v = acc[i][j][r];
                    if (MODE == 0) {
                        v = (v + bias[n]) * scale[n];
                        ((__bf16*)Cout)[(long)z * sCb + (long)m * ldc + n] = (__bf16)v;
                    } else if (MODE == 1) {
                        ((__bf16*)Cout)[(long)z * sCb + (long)m * ldc + n] = (__bf16)v;
                    } else { // MODE 3
                        v = v + bias[n];
                        v = v > 0.f ? v : 0.f;
                        v += addx[(long)m * ldc + n];
                        ((float*)Cout)[(long)m * ldc + n] = v;
                    }
                }
            }
        }
    }
}

// ---------------------------------------------------------------------------
// Fused: x (f32) -> xb (bf16)  AND  xbT[b][c][m] (m padded to 192) transpose.
// ---------------------------------------------------------------------------
__global__ __launch_bounds__(256) void convert_transpose_x(
    const float* __restrict__ x, __bf16* __restrict__ xb, __bf16* __restrict__ xbT)
{
    const int c0 = (blockIdx.x % 12) * 64;
    const int b  = blockIdx.x / 12;
    __shared__ __bf16 lds[64 * 194];
    const int t = threadIdx.x;

    // 180 rows x 16 float4 = 2880 vec loads per block
    for (int i = 0; i < 12; ++i) {
        int idx = i * 256 + t;
        if (idx < 2880) {
            int m = idx >> 4, c4 = idx & 15;
            float4 v = *reinterpret_cast<const float4*>(
                &x[((long)(b * NN + m)) * CC + c0 + c4 * 4]);
            bf16x4 o;
            o[0] = (__bf16)v.x; o[1] = (__bf16)v.y;
            o[2] = (__bf16)v.z; o[3] = (__bf16)v.w;
            *reinterpret_cast<bf16x4*>(&xb[((long)(b * NN + m)) * CC + c0 + c4 * 4]) = o;
            lds[(c4 * 4 + 0) * 194 + m] = o[0];
            lds[(c4 * 4 + 1) * 194 + m] = o[1];
            lds[(c4 * 4 + 2) * 194 + m] = o[2];
            lds[(c4 * 4 + 3) * 194 + m] = o[3];
        }
    }
    __syncthreads();
    for (int j = 0; j < 48; ++j) {
        int idx = j * 256 + t;
        int c = idx / KPAD, m = idx % KPAD;
        __bf16 v = (m < NN) ? lds[c * 194 + m] : (__bf16)0.0f;
        xbT[((long)(b * CC + c0 + c)) * KPAD + m] = v;
    }
}

// ---------------------------------------------------------------------------
// Weights: WqkT[384][768] = [Wq|Wk]^T (bf16), WgT[768][768] = Wg^T (bf16),
// plus combined bias[384] and per-column scale[384] (1/sqrt(R) on Q cols).
// ---------------------------------------------------------------------------
__global__ __launch_bounds__(256) void prep_weights(
    const float* __restrict__ Wq, const float* __restrict__ bq,
    const float* __restrict__ Wk, const float* __restrict__ bk,
    const float* __restrict__ Wg,
    __bf16* __restrict__ WqkT, __bf16* __restrict__ WgT,
    float* __restrict__ biasqk, float* __restrict__ scaleqk)
{
    int blk = blockIdx.x, t = threadIdx.x;
    if (blk < 384) {
        int n = blk;
        const float* W = (n < RR) ? Wq : Wk;
        int nn = (n < RR) ? n : n - RR;
        for (int k = t; k < CC; k += 256)
            WqkT[(long)n * CC + k] = (__bf16)W[(long)k * RR + nn];
        if (blk == 0) {
            for (int i = t; i < 384; i += 256) {
                biasqk[i]  = (i < RR) ? bq[i] : bk[i - RR];
                scaleqk[i] = (i < RR) ? rsqrtf((float)RR) : 1.0f;
            }
        }
    } else {
        int n = blk - 384;
        for (int k = t; k < CC; k += 256)
            WgT[(long)n * CC + k] = (__bf16)Wg[(long)k * CC + n];
    }
}

// ---------------------------------------------------------------------------
// Row softmax of S (bf16, [B][180][180]) + combine with alpha/A_phys,
// write A_comb bf16 [B][180][192] (K-padded with zeros). One wave per row.
// ---------------------------------------------------------------------------
__global__ __launch_bounds__(256) void softmax_combine(
    const __bf16* __restrict__ S, const float* __restrict__ A_phys,
    const float* __restrict__ alpha, __bf16* __restrict__ Acomb)
{
    const int w = threadIdx.x >> 6, l = threadIdx.x & 63;
    const long row = (long)blockIdx.x * 4 + w;
    const int b = (int)(row / NN), n = (int)(row % NN);
    const __bf16* Srow = S + ((long)b * NN + n) * NN;

    float v[3];
#pragma unroll
    for (int i = 0; i < 3; ++i) {
        int m = l + 64 * i;
        v[i] = (m < NN) ? (float)Srow[m] : -1e30f;
    }
    float mx = fmaxf(fmaxf(v[0], v[1]), v[2]);
    for (int off = 32; off; off >>= 1) mx = fmaxf(mx, __shfl_xor(mx, off, 64));

    float e[3], sum = 0.f;
#pragma unroll
    for (int i = 0; i < 3; ++i) {
        int m = l + 64 * i;
        e[i] = (m < NN) ? expf(v[i] - mx) : 0.f;
        sum += e[i];
    }
    for (int off = 32; off; off >>= 1) sum += __shfl_xor(sum, off, 64);

    const float a   = 1.f / (1.f + expf(-alpha[0]));
    const float inv = (1.f - a) / sum;
    __bf16* Orow = Acomb + ((long)b * NN + n) * KPAD;
#pragma unroll
    for (int i = 0; i < 3; ++i) {
        int m = l + 64 * i;
        if (m < KPAD) {
            float o = (m < NN) ? (a * A_phys[n * NN + m] + e[i] * inv) : 0.f;
            Orow[m] = (__bf16)o;
        }
    }
}

// ---------------------------------------------------------------------------
// In-place LayerNorm over channel dim; one block per row of 768.
// ---------------------------------------------------------------------------
__global__ __launch_bounds__(256) void ln_kernel(float* __restrict__ out,
                                                 const float* __restrict__ gamma,
                                                 const float* __restrict__ beta)
{
    float* p = out + (long)blockIdx.x * CC;
    const int t = threadIdx.x, w = t >> 6, l = t & 63;
    float h[3], s = 0.f, s2 = 0.f;
#pragma unroll
    for (int i = 0; i < 3; ++i) {
        h[i] = p[t + 256 * i];
        s += h[i]; s2 += h[i] * h[i];
    }
    for (int off = 32; off; off >>= 1) { s += __shfl_xor(s, off, 64); s2 += __shfl_xor(s2, off, 64); }
    __shared__ float ps[4], ps2[4];
    if (l == 0) { ps[w] = s; ps2[w] = s2; }
    __syncthreads();
    s  = ps[0] + ps[1] + ps[2] + ps[3];
    s2 = ps2[0] + ps2[1] + ps2[2] + ps2[3];
    const float mu  = s * (1.f / CC);
    const float var = s2 * (1.f / CC) - mu * mu;
    const float rs  = rsqrtf(var + 1e-5f);
#pragma unroll
    for (int i = 0; i < 3; ++i) {
        int c = t + 256 * i;
        p[c] = (h[i] - mu) * rs * gamma[c] + beta[c];
    }
}

// ---------------------------------------------------------------------------
extern "C" void kernel_launch(void* const* d_in, const int* in_sizes, int n_in,
                              void* d_out, int out_size, void* d_ws, size_t ws_size,
                              hipStream_t stream)
{
    const float* x      = (const float*)d_in[0];
    const float* Wq     = (const float*)d_in[1];
    const float* bq     = (const float*)d_in[2];
    const float* Wk     = (const float*)d_in[3];
    const float* bk     = (const float*)d_in[4];
    const float* Wg     = (const float*)d_in[5];
    const float* bg     = (const float*)d_in[6];
    const float* gamma  = (const float*)d_in[7];
    const float* beta   = (const float*)d_in[8];
    const float* alpha  = (const float*)d_in[9];
    const float* A_phys = (const float*)d_in[10];

    // ---- workspace carve (bytes). Lifetime aliases: z over xb, Acomb over QK.
    char* w = (char*)d_ws;
    __bf16* xb    = (__bf16*)(w + 0);                       // 70,778,880  (also z)
    __bf16* zbuf  = xb;
    __bf16* xbT   = (__bf16*)(w + 70778880);                // 75,497,472
    __bf16* QK    = (__bf16*)(w + 146276352);               // 35,389,440  (also Acomb)
    __bf16* Acomb = QK;
    __bf16* S     = (__bf16*)(w + 181665792);               // 16,588,800
    __bf16* WqkT  = (__bf16*)(w + 198254592);               //    589,824
    __bf16* WgT   = (__bf16*)(w + 198844416);               //  1,179,648
    float*  biasqk  = (float*)(w + 200024064);              //      1,536
    float*  scaleqk = (float*)(w + 200025600);              //      1,536

    // 1) weight prep + fused x convert/transpose
    prep_weights<<<384 + CC, 256, 0, stream>>>(Wq, bq, Wk, bk, Wg, WqkT, WgT, biasqk, scaleqk);
    convert_transpose_x<<<BB * 12, 256, 0, stream>>>(x, xb, xbT);

    // 2) GEMM1: [46080,768] @ WqkT^T -> QK [46080,384] bf16 (Q scaled by 1/sqrt(R))
    gemm128<0><<<dim3(384 / 128, MROWS / 128, 1), 256, 0, stream>>>(
        xb, CC, 0L, WqkT, CC, 0L, QK, 384, 0L,
        MROWS, 384, CC, biasqk, scaleqk, nullptr);

    // 3) GEMM2 (batched): S[b] = Q[b] (180x192) @ K[b]^T -> [180,180] bf16
    gemm128<1><<<dim3(2, 2, BB), 256, 0, stream>>>(
        QK, 384, (long)NN * 384, QK + RR, 384, (long)NN * 384,
        S, NN, (long)NN * NN,
        NN, NN, RR, nullptr, nullptr, nullptr);

    // 4) softmax + alpha combine -> Acomb [B][180][192] bf16 (overwrites QK region)
    softmax_combine<<<MROWS / 4, 256, 0, stream>>>(S, A_phys, alpha, Acomb);

    // 5) GEMM3 (batched): z[b] = Acomb[b] (180x192) @ xbT[b]^T (192x768) -> bf16
    gemm128<1><<<dim3(CC / 128, 2, BB), 256, 0, stream>>>(
        Acomb, KPAD, (long)NN * KPAD, xbT, KPAD, (long)CC * KPAD,
        zbuf, CC, (long)NN * CC,
        NN, CC, KPAD, nullptr, nullptr, nullptr);

    // 6) GEMM4: h = x + relu(z @ Wg + bg) -> d_out f32 [46080,768]
    gemm128<3><<<dim3(CC / 128, MROWS / 128, 1), 256, 0, stream>>>(
        zbuf, CC, 0L, WgT, CC, 0L, d_out, CC, 0L,
        MROWS, CC, CC, bg, nullptr, x);

    // 7) in-place LayerNorm
    ln_kernel<<<MROWS, 256, 0, stream>>>((float*)d_out, gamma, beta);
}